// Round 13
// baseline (113.133 us; speedup 1.0000x reference)
//
#include <hip/hip_runtime.h>
#include <stdint.h>

typedef __attribute__((ext_vector_type(8))) _Float16 f16x8;
typedef __attribute__((ext_vector_type(4))) float f32x4;

#define MARG 0.09375f

// async global->LDS, 16B per lane
__device__ __forceinline__ void glds16(const void* g, void* l) {
  __builtin_amdgcn_global_load_lds(
      (const __attribute__((address_space(1))) void*)g,
      (__attribute__((address_space(3))) void*)l, 16, 0, 0);
}

__device__ __forceinline__ unsigned short f2h(float f) {
  return __builtin_bit_cast(unsigned short, (_Float16)f);  // RN
}

// ---------------- prep cb: fp16 convert + hc[k] = 0.5*|c_k|^2; zero counter -------
__global__ __launch_bounds__(256) void vq_prep_cb(const float* __restrict__ cb,
                                                  unsigned short* __restrict__ cbh,
                                                  float* __restrict__ hc,
                                                  int* __restrict__ count) {
  int w = threadIdx.x >> 6, lane = threadIdx.x & 63;
  int row = blockIdx.x * 4 + w;
  size_t off = (size_t)row * 256 + lane * 4;
  float4 v = *reinterpret_cast<const float4*>(cb + off);
  ushort4 h;
  h.x = f2h(v.x); h.y = f2h(v.y); h.z = f2h(v.z); h.w = f2h(v.w);
  *reinterpret_cast<ushort4*>(cbh + off) = h;
  float s = v.x * v.x + v.y * v.y + v.z * v.z + v.w * v.w;
#pragma unroll
  for (int m = 32; m >= 1; m >>= 1) s += __shfl_xor(s, m, 64);
  if (lane == 0) hc[row] = 0.5f * s;
  if (blockIdx.x == 0 && threadIdx.x == 0) *count = 0;
}

// ---- main: fp16 MFMA GEMM, A in registers, single-barrier depth-3 B pipeline ----
// 512 thr = 8 waves (4M x 2N), wave tile 16 rows x 64 codes. Block: 64 rows x 1024
// codes as 8 chunks of 128 codes x 4 K-steps of 64 dims = 32 steps. Per step:
// {vmcnt(2)+lgkmcnt(0) ; s_barrier ; stage(T+2)->buf (T+2)%3 ; 8 ds_read ; 8 MFMA}.
// lgkmcnt(0) before the barrier drains this wave's reads of buf (T-1)%3; the
// barrier then makes the overwrite (stage) safe. Counted vmcnt(2) keeps one
// stage in flight across the barrier (T4). A_lds aliases Blds[0..32KB) in phase 0.
__global__ __launch_bounds__(512, 4) void vq_mfma_kernel(
    const float* __restrict__ x, const unsigned short* __restrict__ cbh,
    const float* __restrict__ hc, int* __restrict__ out,
    int* __restrict__ list, int* __restrict__ count) {
  __shared__ unsigned short Blds[3 * 8192];  // 48 KB (3 bufs x 128 codes x 64 dims)
  __shared__ float c2s[1024];                // 4 KB
  __shared__ float cbv[2][64];               // cross-wave merge: best
  __shared__ int   cbi[2][64];               //   index
  __shared__ float csv[2][64];               //   second-best

  const int tid = threadIdx.x;
  const int lane = tid & 63;
  const int wave = tid >> 6;
  const int wr = wave >> 1;   // 0..3 (row block of 16)
  const int wc = wave & 1;    // 0..1 (code half of 64 within 128-chunk)
  const int l15 = lane & 15;
  const int l4  = lane >> 4;  // 0..3
  // XCD-aware swizzle: 512 blocks, 8 XCDs -> contiguous 64-block chunks per XCD
  const int bswz = (blockIdx.x & 7) * 64 + (blockIdx.x >> 3);
  const int r0 = bswz * 64;

  reinterpret_cast<float2*>(c2s)[tid] = reinterpret_cast<const float2*>(hc)[tid];

  // ---- Phase 0: A rows fp32 -> fp16 -> aliased A_lds (first 32KB of Blds) ----
  {
    const int row = tid >> 3;          // 0..63
    const int cc  = tid & 7;           // col chunk (32 dims)
    const float* src = x + (size_t)(r0 + row) * 256 + cc * 32;
    unsigned short hv[32];
#pragma unroll
    for (int q = 0; q < 8; ++q) {
      float4 v = *reinterpret_cast<const float4*>(src + q * 4);
      hv[q * 4 + 0] = f2h(v.x); hv[q * 4 + 1] = f2h(v.y);
      hv[q * 4 + 2] = f2h(v.z); hv[q * 4 + 3] = f2h(v.w);
    }
    char* base = reinterpret_cast<char*>(Blds);
#pragma unroll
    for (int g = 0; g < 4; ++g) {
      int byte = (row * 512 + cc * 64 + g * 16) ^ ((row & 7) << 4);
      *reinterpret_cast<f16x8*>(base + byte) = *reinterpret_cast<const f16x8*>(&hv[g * 8]);
    }
  }
  __syncthreads();   // A_lds complete

  // ---- hoist this lane's 8 A fragments (row = wr*16+l15) to registers ----
  f16x8 af[8];
  {
    const char* Ab = reinterpret_cast<const char*>(Blds);
    int arow = wr * 16 + l15;
    int abase = (arow * 512 + l4 * 16) ^ ((arow & 7) << 4);
#pragma unroll
    for (int dt = 0; dt < 8; ++dt)
      af[dt] = *reinterpret_cast<const f16x8*>(Ab + (abase ^ (dt * 64)));
  }
  __syncthreads();   // alias region free for B staging

  // B staging: 1024 granules (16B), 2/thread, linear dest; source granule
  // pre-swizzled by (code&7) so reads XOR the same involution (bank spread).
  auto stage = [&](int T1, int buf) {
    const int n0 = (T1 >> 2) << 7;   // code base (128-chunk)
    const int d0 = (T1 & 3) << 6;    // dim base (64)
    unsigned short* B = Blds + buf * 8192;
#pragma unroll
    for (int r = 0; r < 2; ++r) {
      int idx = r * 512 + tid;
      int c = idx >> 3;
      int lg = (idx & 7) ^ (c & 7);
      glds16(cbh + (size_t)(n0 + c) * 256 + d0 + lg * 8, B + idx * 8);
    }
  };

  float bestv[4], secv[4];
  int besti[4];
#pragma unroll
  for (int g = 0; g < 4; ++g) {
    bestv[g] = -3.4e38f; secv[g] = -3.4e38f; besti[g] = 0;
  }

  stage(0, 0);
  stage(1, 1);

#pragma unroll
  for (int nt = 0; nt < 8; ++nt) {
    f32x4 acc[4];
#pragma unroll
    for (int tcx = 0; tcx < 4; ++tcx) acc[tcx] = (f32x4){0.f, 0.f, 0.f, 0.f};

#pragma unroll
    for (int s = 0; s < 4; ++s) {
      const int T = nt * 4 + s;
      // stage(T) landed? (2 loads of stage T+1 may stay in flight) + my reads
      // of buf (T-1)%3 fully drained before signaling the barrier.
      if (T < 31) {
        asm volatile("s_waitcnt vmcnt(2) lgkmcnt(0)" ::: "memory");
      } else {
        asm volatile("s_waitcnt vmcnt(0) lgkmcnt(0)" ::: "memory");
      }
      asm volatile("s_barrier" ::: "memory");
      // safe to overwrite buf (T+2)%3 == (T-1)%3 now: everyone passed the barrier
      if (T < 30) stage(T + 2, (T + 2) % 3);

      const unsigned short* B = Blds + (T % 3) * 8192;
      __builtin_amdgcn_s_setprio(1);
#pragma unroll
      for (int kk = 0; kk < 2; ++kk) {
        f16x8 bf[4];
#pragma unroll
        for (int tcx = 0; tcx < 4; ++tcx) {
          int c = wc * 64 + tcx * 16 + l15;          // local code 0..127
          int phys = (kk * 4 + l4) ^ (c & 7);        // swizzled granule
          bf[tcx] = *reinterpret_cast<const f16x8*>(B + c * 64 + phys * 8);
        }
#pragma unroll
        for (int tcx = 0; tcx < 4; ++tcx)
          acc[tcx] = __builtin_amdgcn_mfma_f32_16x16x32_f16(
              af[s * 2 + kk], bf[tcx], acc[tcx], 0, 0, 0);
      }
      __builtin_amdgcn_s_setprio(0);
    }

    // fold 128-code chunk into running best/second (codes ascending)
    const int cb0 = nt * 128 + wc * 64 + l15;
#pragma unroll
    for (int tcx = 0; tcx < 4; ++tcx) {
      const int code = cb0 + tcx * 16;
      const float hcv = c2s[code];
#pragma unroll
      for (int g = 0; g < 4; ++g) {
        float sc = acc[tcx][g] - hcv;
        bool gt = sc > bestv[g];
        float ns = gt ? bestv[g] : fmaxf(secv[g], sc);
        bestv[g] = gt ? sc : bestv[g];
        besti[g] = gt ? code : besti[g];
        secv[g] = ns;
      }
    }
  }

  // within-wave merge across the 16 l15-lanes sharing each row-slot
#pragma unroll
  for (int g = 0; g < 4; ++g) {
    float bv = bestv[g]; int bi = besti[g]; float sv = secv[g];
#pragma unroll
    for (int m = 1; m < 16; m <<= 1) {
      float ov = __shfl_xor(bv, m, 64);
      int   oi = __shfl_xor(bi, m, 64);
      float os = __shfl_xor(sv, m, 64);
      sv = fmaxf(fmaxf(sv, os), fminf(bv, ov));
      bool gt = (ov > bv) || (ov == bv && oi < bi);
      bv = gt ? ov : bv;
      bi = gt ? oi : bi;
    }
    if (l15 == 0) {
      int rl = wr * 16 + l4 * 4 + g;
      cbv[wc][rl] = bv; cbi[wc][rl] = bi; csv[wc][rl] = sv;
    }
  }

  // cross-wave merge: 2 wc-waves surveyed disjoint 64-code halves per chunk
  __syncthreads();
  if (tid < 64) {
    float bv = cbv[0][tid]; int bi = cbi[0][tid]; float sv = csv[0][tid];
    float ov = cbv[1][tid]; int oi = cbi[1][tid]; float os = csv[1][tid];
    sv = fmaxf(fmaxf(sv, os), fminf(bv, ov));
    bool gt = (ov > bv) || (ov == bv && oi < bi);
    bv = gt ? ov : bv;
    bi = gt ? oi : bi;
    out[r0 + tid] = bi;
    if (sv >= bv - MARG) {           // ambiguous: append to compact recheck list
      int slot = atomicAdd(count, 1);
      list[slot] = r0 + tid;
    }
  }
}

// -------- cleanup v5: exact fp32 recompute, 8 rows/unit (VALU ~= L2-stream) -------
__global__ __launch_bounds__(512) void vq_cleanup(const float* __restrict__ x,
                                                  const float* __restrict__ cb,
                                                  const float* __restrict__ hc,
                                                  const int* __restrict__ list,
                                                  const int* __restrict__ count,
                                                  int* __restrict__ out) {
  __shared__ float xt[8][256];    // 8 KB
  __shared__ int rowids[8];
  __shared__ float wbv[8][8];
  __shared__ int   wbi[8][8];
  const int tid = threadIdx.x;
  const int wave = tid >> 6;
  const int n = *count;

  for (int t0 = blockIdx.x * 8; t0 < n; t0 += gridDim.x * 8) {
    __syncthreads();  // protect LDS reuse across grid-stride iterations
    if (tid < 8) rowids[tid] = (t0 + tid < n) ? list[t0 + tid] : -1;
    __syncthreads();
    {
      int j = tid >> 6, seg = tid & 63;
      int row = rowids[j];
      if (row < 0) row = rowids[0];  // dead slot: stage any valid row (result unused)
      *reinterpret_cast<float4*>(&xt[j][seg * 4]) =
          *reinterpret_cast<const float4*>(x + (size_t)row * 256 + seg * 4);
    }
    __syncthreads();

    float acc0[8], acc1[8];
#pragma unroll
    for (int j = 0; j < 8; ++j) { acc0[j] = 0.f; acc1[j] = 0.f; }

    const float* c0 = cb + (size_t)tid * 256;
    const float* c1 = cb + (size_t)(512 + tid) * 256;
#pragma unroll 4
    for (int d0 = 0; d0 < 256; d0 += 4) {
      float4 ca = *reinterpret_cast<const float4*>(c0 + d0);
      float4 cd = *reinterpret_cast<const float4*>(c1 + d0);
#pragma unroll
      for (int j = 0; j < 8; ++j) {
        float4 xv = *reinterpret_cast<const float4*>(&xt[j][d0]);  // wave-broadcast
        acc0[j] = fmaf(ca.x, xv.x, acc0[j]);
        acc0[j] = fmaf(ca.y, xv.y, acc0[j]);
        acc0[j] = fmaf(ca.z, xv.z, acc0[j]);
        acc0[j] = fmaf(ca.w, xv.w, acc0[j]);
        acc1[j] = fmaf(cd.x, xv.x, acc1[j]);
        acc1[j] = fmaf(cd.y, xv.y, acc1[j]);
        acc1[j] = fmaf(cd.z, xv.z, acc1[j]);
        acc1[j] = fmaf(cd.w, xv.w, acc1[j]);
      }
    }

    const float h0 = hc[tid];
    const float h1 = hc[512 + tid];

#pragma unroll
    for (int j = 0; j < 8; ++j) {
      float bv = acc0[j] - h0; int bi = tid;
      float s1 = acc1[j] - h1;
      if (s1 > bv) { bv = s1; bi = 512 + tid; }  // codes ascending -> strict >
#pragma unroll
      for (int m = 1; m < 64; m <<= 1) {
        float ov = __shfl_xor(bv, m, 64);
        int   oi = __shfl_xor(bi, m, 64);
        bool gt = (ov > bv) || (ov == bv && oi < bi);
        bv = gt ? ov : bv;
        bi = gt ? oi : bi;
      }
      if ((tid & 63) == 0) { wbv[wave][j] = bv; wbi[wave][j] = bi; }
    }
    __syncthreads();
    if (tid < 8 && rowids[tid] >= 0) {
      float bv = wbv[0][tid]; int bi = wbi[0][tid];
#pragma unroll
      for (int w2 = 1; w2 < 8; ++w2) {
        float ov = wbv[w2][tid]; int oi = wbi[w2][tid];
        if (ov > bv || (ov == bv && oi < bi)) { bv = ov; bi = oi; }
      }
      out[rowids[tid]] = bi;
    }
  }
}

// ================= fallback fp32 path (R2 kernel) if ws is too small =================
#define BM 128
#define BN 256
#define BD 32
#define NT 512

__global__ __launch_bounds__(256) void vq_c2_kernel(const float* __restrict__ cb,
                                                    float* __restrict__ halfc2) {
  int row  = blockIdx.x * 4 + (threadIdx.x >> 6);
  int lane = threadIdx.x & 63;
  float4 v = *reinterpret_cast<const float4*>(cb + (size_t)row * 256 + lane * 4);
  float s = v.x * v.x + v.y * v.y + v.z * v.z + v.w * v.w;
#pragma unroll
  for (int m = 32; m >= 1; m >>= 1) s += __shfl_xor(s, m, 64);
  if (lane == 0) halfc2[row] = 0.5f * s;
}

__global__ __launch_bounds__(NT, 2) void vq_argmin_kernel(
    const float* __restrict__ x, const float* __restrict__ cb,
    const float* __restrict__ halfc2, int* __restrict__ out) {
  __shared__ float lds[2][(BM + BN) * BD];
  __shared__ float c2s[1024];
  const int tid = threadIdx.x;
  const int w   = tid >> 6;
  const int tc  = tid & 31;
  const int tr  = tid >> 5;
  const int r0  = blockIdx.x * BM;
  reinterpret_cast<float2*>(c2s)[tid] = reinterpret_cast<const float2*>(halfc2)[tid];
  const int sA  = tr & 7;
  const int sB  = tc & 7;
  const int sAB = sA ^ sB;
  const int cho = (((tid & 7) ^ w)) * 4;
  const int sub = tid >> 3;
  float bestv[8]; int besti[8];
#pragma unroll
  for (int i = 0; i < 8; ++i) { bestv[i] = -3.4e38f; besti[i] = 0; }
  auto stage = [&](int n0, int d0, int p) {
    float* dst  = &lds[p][0];
    float* dstB = dst + BM * BD;
#pragma unroll
    for (int r = 0; r < 2; ++r) {
      int t2 = r * NT + tid;
      glds16(x + (size_t)(r0 + r * 64 + sub) * 256 + d0 + cho, dst + t2 * 4);
    }
#pragma unroll
    for (int r = 0; r < 4; ++r) {
      int t2 = r * NT + tid;
      glds16(cb + (size_t)(n0 + r * 64 + sub) * 256 + d0 + cho, dstB + t2 * 4);
    }
  };
  stage(0, 0, 0);
  int t = 0;
  for (int nt = 0; nt < 4; ++nt) {
    float acc[8][8];
#pragma unroll
    for (int i = 0; i < 8; ++i)
#pragma unroll
      for (int j = 0; j < 8; ++j) acc[i][j] = 0.f;
    for (int dt = 0; dt < 8; ++dt, ++t) {
      const int p = t & 1;
      if (t < 31) {
        const int t1 = t + 1;
        stage((t1 >> 3) * BN, (t1 & 7) * BD, t1 & 1);
        asm volatile("s_waitcnt vmcnt(6)" ::: "memory");
      } else {
        asm volatile("s_waitcnt vmcnt(0)" ::: "memory");
      }
      __builtin_amdgcn_s_barrier();
      const float* pA = &lds[p][tr * 8 * BD];
      const float* pB = &lds[p][BM * BD + tc * 8 * BD];
#pragma unroll
      for (int cc = 0; cc < 8; ++cc) {
        const float* pBc = pB + ((cc ^ sAB) << 2);
        float4 a[8], b[8];
#pragma unroll
        for (int i = 0; i < 8; ++i)
          a[i] = *reinterpret_cast<const float4*>(pA + i * BD + cc * 4);
#pragma unroll
        for (int j = 0; j < 8; ++j)
          b[j] = *reinterpret_cast<const float4*>(pBc + j * BD);
#pragma unroll
        for (int i = 0; i < 8; ++i)
#pragma unroll
          for (int j = 0; j < 8; ++j) {
            acc[i][j] = fmaf(a[i].x, b[j].x, acc[i][j]);
            acc[i][j] = fmaf(a[i].y, b[j].y, acc[i][j]);
            acc[i][j] = fmaf(a[i].z, b[j].z, acc[i][j]);
            acc[i][j] = fmaf(a[i].w, b[j].w, acc[i][j]);
          }
      }
      asm volatile("s_waitcnt lgkmcnt(0)" ::: "memory");
      __builtin_amdgcn_s_barrier();
    }
    const int n0 = nt * BN;
#pragma unroll
    for (int j = 0; j < 8; ++j) {
      const int code = n0 + tc * 8 + j;
      const float hc = c2s[code];
#pragma unroll
      for (int i = 0; i < 8; ++i) {
        float s = acc[i][j] - hc;
        if (s > bestv[i]) { bestv[i] = s; besti[i] = code; }
      }
    }
  }
#pragma unroll
  for (int i = 0; i < 8; ++i) {
#pragma unroll
    for (int m = 1; m <= 16; m <<= 1) {
      float ov = __shfl_xor(bestv[i], m, 64);
      int   oi = __shfl_xor(besti[i], m, 64);
      if (ov > bestv[i] || (ov == bestv[i] && oi < besti[i])) { bestv[i] = ov; besti[i] = oi; }
    }
  }
  if (tc == 0) {
#pragma unroll
    for (int i = 0; i < 8; ++i) out[r0 + tr * 8 + i] = besti[i];
  }
}

// ==================================== launch ====================================
extern "C" void kernel_launch(void* const* d_in, const int* in_sizes, int n_in,
                              void* d_out, int out_size, void* d_ws, size_t ws_size,
                              hipStream_t stream) {
  const float* x  = (const float*)d_in[0];   // (8,4096,256) fp32
  const float* cb = (const float*)d_in[1];   // (1024,256) fp32
  int* out = (int*)d_out;                    // (8,4096) int32

  // ws layout (bytes): cbh 512K | hc 4K | list 128K | count 4
  const size_t OFF_CH = 0;
  const size_t OFF_HC = OFF_CH + (size_t)1024 * 256 * 2;
  const size_t OFF_LS = OFF_HC + (size_t)1024 * 4;
  const size_t OFF_CT = OFF_LS + (size_t)32768 * 4;
  const size_t NEED   = OFF_CT + 64;

  if (ws_size >= NEED) {
    unsigned short* cbh = (unsigned short*)((char*)d_ws + OFF_CH);
    float* hc  = (float*)((char*)d_ws + OFF_HC);
    int* list  = (int*)((char*)d_ws + OFF_LS);
    int* count = (int*)((char*)d_ws + OFF_CT);

    hipLaunchKernelGGL(vq_prep_cb, dim3(256), dim3(256), 0, stream, cb, cbh, hc, count);
    hipLaunchKernelGGL(vq_mfma_kernel, dim3(512), dim3(512), 0, stream,
                       x, cbh, hc, out, list, count);
    hipLaunchKernelGGL(vq_cleanup, dim3(512), dim3(512), 0, stream,
                       x, cb, hc, list, count, out);
  } else {
    float* c2 = (float*)d_ws;
    hipLaunchKernelGGL(vq_c2_kernel, dim3(256), dim3(256), 0, stream, cb, c2);
    hipLaunchKernelGGL(vq_argmin_kernel, dim3(32768 / BM), dim3(NT), 0, stream,
                       x, cb, c2, out);
  }
}

// Round 14
// 88.083 us; speedup vs baseline: 1.2844x; 1.2844x over previous
//
#include <hip/hip_runtime.h>
#include <stdint.h>

typedef __attribute__((ext_vector_type(8))) _Float16 f16x8;
typedef __attribute__((ext_vector_type(4))) float f32x4;

#define MARG 0.09375f

// async global->LDS, 16B per lane
__device__ __forceinline__ void glds16(const void* g, void* l) {
  __builtin_amdgcn_global_load_lds(
      (const __attribute__((address_space(1))) void*)g,
      (__attribute__((address_space(3))) void*)l, 16, 0, 0);
}

__device__ __forceinline__ unsigned short f2h(float f) {
  return __builtin_bit_cast(unsigned short, (_Float16)f);  // RN
}

// ---------------- prep cb: fp16 convert + hc[k] = 0.5*|c_k|^2; zero counter -------
__global__ __launch_bounds__(256) void vq_prep_cb(const float* __restrict__ cb,
                                                  unsigned short* __restrict__ cbh,
                                                  float* __restrict__ hc,
                                                  int* __restrict__ count) {
  int w = threadIdx.x >> 6, lane = threadIdx.x & 63;
  int row = blockIdx.x * 4 + w;
  size_t off = (size_t)row * 256 + lane * 4;
  float4 v = *reinterpret_cast<const float4*>(cb + off);
  ushort4 h;
  h.x = f2h(v.x); h.y = f2h(v.y); h.z = f2h(v.z); h.w = f2h(v.w);
  *reinterpret_cast<ushort4*>(cbh + off) = h;
  float s = v.x * v.x + v.y * v.y + v.z * v.z + v.w * v.w;
#pragma unroll
  for (int m = 32; m >= 1; m >>= 1) s += __shfl_xor(s, m, 64);
  if (lane == 0) hc[row] = 0.5f * s;
  if (blockIdx.x == 0 && threadIdx.x == 0) *count = 0;
}

// ---- main: fp16 MFMA GEMM, A in registers, single-barrier depth-3 B pipeline ----
// 512 thr = 8 waves (4M x 2N), wave tile 16 rows x 64 codes. Block: 64 rows x 1024
// codes as 8 chunks of 128 codes x 4 K-steps of 64 dims = 32 steps. Per step:
// {vmcnt(2)+lgkmcnt(0) ; s_barrier ; stage(T+2)->buf (T+2)%3 ; 8 ds_read ; 8 MFMA}.
// NOTE launch_bounds (512,2): empirically arg=4 caps the allocator at 64 VGPR and
// spilled the af[8] fragments to scratch (R13: 119MB HBM writes). arg=2 -> ~128.
__global__ __launch_bounds__(512, 2) void vq_mfma_kernel(
    const float* __restrict__ x, const unsigned short* __restrict__ cbh,
    const float* __restrict__ hc, int* __restrict__ out,
    int* __restrict__ list, int* __restrict__ count) {
  __shared__ unsigned short Blds[3 * 8192];  // 48 KB (3 bufs x 128 codes x 64 dims)
  __shared__ float c2s[1024];                // 4 KB
  __shared__ float cbv[2][64];               // cross-wave merge: best
  __shared__ int   cbi[2][64];               //   index
  __shared__ float csv[2][64];               //   second-best

  const int tid = threadIdx.x;
  const int lane = tid & 63;
  const int wave = tid >> 6;
  const int wr = wave >> 1;   // 0..3 (row block of 16)
  const int wc = wave & 1;    // 0..1 (code half of 64 within 128-chunk)
  const int l15 = lane & 15;
  const int l4  = lane >> 4;  // 0..3
  // XCD-aware swizzle: 512 blocks, 8 XCDs -> contiguous 64-block chunks per XCD
  const int bswz = (blockIdx.x & 7) * 64 + (blockIdx.x >> 3);
  const int r0 = bswz * 64;

  reinterpret_cast<float2*>(c2s)[tid] = reinterpret_cast<const float2*>(hc)[tid];

  // ---- Phase 0: A rows fp32 -> fp16 -> aliased A_lds (first 32KB of Blds) ----
  {
    const int row = tid >> 3;          // 0..63
    const int cc  = tid & 7;           // col chunk (32 dims)
    const float* src = x + (size_t)(r0 + row) * 256 + cc * 32;
    unsigned short hv[32];
#pragma unroll
    for (int q = 0; q < 8; ++q) {
      float4 v = *reinterpret_cast<const float4*>(src + q * 4);
      hv[q * 4 + 0] = f2h(v.x); hv[q * 4 + 1] = f2h(v.y);
      hv[q * 4 + 2] = f2h(v.z); hv[q * 4 + 3] = f2h(v.w);
    }
    char* base = reinterpret_cast<char*>(Blds);
#pragma unroll
    for (int g = 0; g < 4; ++g) {
      int byte = (row * 512 + cc * 64 + g * 16) ^ ((row & 7) << 4);
      *reinterpret_cast<f16x8*>(base + byte) = *reinterpret_cast<const f16x8*>(&hv[g * 8]);
    }
  }
  __syncthreads();   // A_lds complete

  // ---- hoist this lane's 8 A fragments (row = wr*16+l15) to registers ----
  f16x8 af[8];
  {
    const char* Ab = reinterpret_cast<const char*>(Blds);
    int arow = wr * 16 + l15;
    int abase = (arow * 512 + l4 * 16) ^ ((arow & 7) << 4);
#pragma unroll
    for (int dt = 0; dt < 8; ++dt)
      af[dt] = *reinterpret_cast<const f16x8*>(Ab + (abase ^ (dt * 64)));
  }
  __syncthreads();   // alias region free for B staging

  // B staging: 1024 granules (16B), 2/thread, linear dest; source granule
  // pre-swizzled by (code&7) so reads XOR the same involution (bank spread).
  auto stage = [&](int T1, int buf) {
    const int n0 = (T1 >> 2) << 7;   // code base (128-chunk)
    const int d0 = (T1 & 3) << 6;    // dim base (64)
    unsigned short* B = Blds + buf * 8192;
#pragma unroll
    for (int r = 0; r < 2; ++r) {
      int idx = r * 512 + tid;
      int c = idx >> 3;
      int lg = (idx & 7) ^ (c & 7);
      glds16(cbh + (size_t)(n0 + c) * 256 + d0 + lg * 8, B + idx * 8);
    }
  };

  float bestv[4], secv[4];
  int besti[4];
#pragma unroll
  for (int g = 0; g < 4; ++g) {
    bestv[g] = -3.4e38f; secv[g] = -3.4e38f; besti[g] = 0;
  }

  stage(0, 0);
  stage(1, 1);

#pragma unroll
  for (int nt = 0; nt < 8; ++nt) {
    f32x4 acc[4];
#pragma unroll
    for (int tcx = 0; tcx < 4; ++tcx) acc[tcx] = (f32x4){0.f, 0.f, 0.f, 0.f};

#pragma unroll
    for (int s = 0; s < 4; ++s) {
      const int T = nt * 4 + s;
      // stage(T) landed? (2 loads of stage T+1 may stay in flight) + my reads
      // of buf (T-1)%3 fully drained before signaling the barrier.
      if (T < 31) {
        asm volatile("s_waitcnt vmcnt(2) lgkmcnt(0)" ::: "memory");
      } else {
        asm volatile("s_waitcnt vmcnt(0) lgkmcnt(0)" ::: "memory");
      }
      asm volatile("s_barrier" ::: "memory");
      // safe to overwrite buf (T+2)%3 == (T-1)%3 now: everyone passed the barrier
      if (T < 30) stage(T + 2, (T + 2) % 3);

      const unsigned short* B = Blds + (T % 3) * 8192;
      __builtin_amdgcn_s_setprio(1);
#pragma unroll
      for (int kk = 0; kk < 2; ++kk) {
        f16x8 bf[4];
#pragma unroll
        for (int tcx = 0; tcx < 4; ++tcx) {
          int c = wc * 64 + tcx * 16 + l15;          // local code 0..127
          int phys = (kk * 4 + l4) ^ (c & 7);        // swizzled granule
          bf[tcx] = *reinterpret_cast<const f16x8*>(B + c * 64 + phys * 8);
        }
#pragma unroll
        for (int tcx = 0; tcx < 4; ++tcx)
          acc[tcx] = __builtin_amdgcn_mfma_f32_16x16x32_f16(
              af[s * 2 + kk], bf[tcx], acc[tcx], 0, 0, 0);
      }
      __builtin_amdgcn_s_setprio(0);
    }

    // fold 128-code chunk into running best/second (codes ascending)
    const int cb0 = nt * 128 + wc * 64 + l15;
#pragma unroll
    for (int tcx = 0; tcx < 4; ++tcx) {
      const int code = cb0 + tcx * 16;
      const float hcv = c2s[code];
#pragma unroll
      for (int g = 0; g < 4; ++g) {
        float sc = acc[tcx][g] - hcv;
        bool gt = sc > bestv[g];
        float ns = gt ? bestv[g] : fmaxf(secv[g], sc);
        bestv[g] = gt ? sc : bestv[g];
        besti[g] = gt ? code : besti[g];
        secv[g] = ns;
      }
    }
  }

  // within-wave merge across the 16 l15-lanes sharing each row-slot
#pragma unroll
  for (int g = 0; g < 4; ++g) {
    float bv = bestv[g]; int bi = besti[g]; float sv = secv[g];
#pragma unroll
    for (int m = 1; m < 16; m <<= 1) {
      float ov = __shfl_xor(bv, m, 64);
      int   oi = __shfl_xor(bi, m, 64);
      float os = __shfl_xor(sv, m, 64);
      sv = fmaxf(fmaxf(sv, os), fminf(bv, ov));
      bool gt = (ov > bv) || (ov == bv && oi < bi);
      bv = gt ? ov : bv;
      bi = gt ? oi : bi;
    }
    if (l15 == 0) {
      int rl = wr * 16 + l4 * 4 + g;
      cbv[wc][rl] = bv; cbi[wc][rl] = bi; csv[wc][rl] = sv;
    }
  }

  // cross-wave merge: 2 wc-waves surveyed disjoint 64-code halves per chunk
  __syncthreads();
  if (tid < 64) {
    float bv = cbv[0][tid]; int bi = cbi[0][tid]; float sv = csv[0][tid];
    float ov = cbv[1][tid]; int oi = cbi[1][tid]; float os = csv[1][tid];
    sv = fmaxf(fmaxf(sv, os), fminf(bv, ov));
    bool gt = (ov > bv) || (ov == bv && oi < bi);
    bv = gt ? ov : bv;
    bi = gt ? oi : bi;
    out[r0 + tid] = bi;
    if (sv >= bv - MARG) {           // ambiguous: append to compact recheck list
      int slot = atomicAdd(count, 1);
      list[slot] = r0 + tid;
    }
  }
}

// -------- cleanup v5: exact fp32 recompute, 8 rows/unit (VALU ~= L2-stream) -------
__global__ __launch_bounds__(512) void vq_cleanup(const float* __restrict__ x,
                                                  const float* __restrict__ cb,
                                                  const float* __restrict__ hc,
                                                  const int* __restrict__ list,
                                                  const int* __restrict__ count,
                                                  int* __restrict__ out) {
  __shared__ float xt[8][256];    // 8 KB
  __shared__ int rowids[8];
  __shared__ float wbv[8][8];
  __shared__ int   wbi[8][8];
  const int tid = threadIdx.x;
  const int wave = tid >> 6;
  const int n = *count;

  for (int t0 = blockIdx.x * 8; t0 < n; t0 += gridDim.x * 8) {
    __syncthreads();  // protect LDS reuse across grid-stride iterations
    if (tid < 8) rowids[tid] = (t0 + tid < n) ? list[t0 + tid] : -1;
    __syncthreads();
    {
      int j = tid >> 6, seg = tid & 63;
      int row = rowids[j];
      if (row < 0) row = rowids[0];  // dead slot: stage any valid row (result unused)
      *reinterpret_cast<float4*>(&xt[j][seg * 4]) =
          *reinterpret_cast<const float4*>(x + (size_t)row * 256 + seg * 4);
    }
    __syncthreads();

    float acc0[8], acc1[8];
#pragma unroll
    for (int j = 0; j < 8; ++j) { acc0[j] = 0.f; acc1[j] = 0.f; }

    const float* c0 = cb + (size_t)tid * 256;
    const float* c1 = cb + (size_t)(512 + tid) * 256;
#pragma unroll 4
    for (int d0 = 0; d0 < 256; d0 += 4) {
      float4 ca = *reinterpret_cast<const float4*>(c0 + d0);
      float4 cd = *reinterpret_cast<const float4*>(c1 + d0);
#pragma unroll
      for (int j = 0; j < 8; ++j) {
        float4 xv = *reinterpret_cast<const float4*>(&xt[j][d0]);  // wave-broadcast
        acc0[j] = fmaf(ca.x, xv.x, acc0[j]);
        acc0[j] = fmaf(ca.y, xv.y, acc0[j]);
        acc0[j] = fmaf(ca.z, xv.z, acc0[j]);
        acc0[j] = fmaf(ca.w, xv.w, acc0[j]);
        acc1[j] = fmaf(cd.x, xv.x, acc1[j]);
        acc1[j] = fmaf(cd.y, xv.y, acc1[j]);
        acc1[j] = fmaf(cd.z, xv.z, acc1[j]);
        acc1[j] = fmaf(cd.w, xv.w, acc1[j]);
      }
    }

    const float h0 = hc[tid];
    const float h1 = hc[512 + tid];

#pragma unroll
    for (int j = 0; j < 8; ++j) {
      float bv = acc0[j] - h0; int bi = tid;
      float s1 = acc1[j] - h1;
      if (s1 > bv) { bv = s1; bi = 512 + tid; }  // codes ascending -> strict >
#pragma unroll
      for (int m = 1; m < 64; m <<= 1) {
        float ov = __shfl_xor(bv, m, 64);
        int   oi = __shfl_xor(bi, m, 64);
        bool gt = (ov > bv) || (ov == bv && oi < bi);
        bv = gt ? ov : bv;
        bi = gt ? oi : bi;
      }
      if ((tid & 63) == 0) { wbv[wave][j] = bv; wbi[wave][j] = bi; }
    }
    __syncthreads();
    if (tid < 8 && rowids[tid] >= 0) {
      float bv = wbv[0][tid]; int bi = wbi[0][tid];
#pragma unroll
      for (int w2 = 1; w2 < 8; ++w2) {
        float ov = wbv[w2][tid]; int oi = wbi[w2][tid];
        if (ov > bv || (ov == bv && oi < bi)) { bv = ov; bi = oi; }
      }
      out[rowids[tid]] = bi;
    }
  }
}

// ================= fallback fp32 path (R2 kernel) if ws is too small =================
#define BM 128
#define BN 256
#define BD 32
#define NT 512

__global__ __launch_bounds__(256) void vq_c2_kernel(const float* __restrict__ cb,
                                                    float* __restrict__ halfc2) {
  int row  = blockIdx.x * 4 + (threadIdx.x >> 6);
  int lane = threadIdx.x & 63;
  float4 v = *reinterpret_cast<const float4*>(cb + (size_t)row * 256 + lane * 4);
  float s = v.x * v.x + v.y * v.y + v.z * v.z + v.w * v.w;
#pragma unroll
  for (int m = 32; m >= 1; m >>= 1) s += __shfl_xor(s, m, 64);
  if (lane == 0) halfc2[row] = 0.5f * s;
}

__global__ __launch_bounds__(NT, 2) void vq_argmin_kernel(
    const float* __restrict__ x, const float* __restrict__ cb,
    const float* __restrict__ halfc2, int* __restrict__ out) {
  __shared__ float lds[2][(BM + BN) * BD];
  __shared__ float c2s[1024];
  const int tid = threadIdx.x;
  const int w   = tid >> 6;
  const int tc  = tid & 31;
  const int tr  = tid >> 5;
  const int r0  = blockIdx.x * BM;
  reinterpret_cast<float2*>(c2s)[tid] = reinterpret_cast<const float2*>(halfc2)[tid];
  const int sA  = tr & 7;
  const int sB  = tc & 7;
  const int sAB = sA ^ sB;
  const int cho = (((tid & 7) ^ w)) * 4;
  const int sub = tid >> 3;
  float bestv[8]; int besti[8];
#pragma unroll
  for (int i = 0; i < 8; ++i) { bestv[i] = -3.4e38f; besti[i] = 0; }
  auto stage = [&](int n0, int d0, int p) {
    float* dst  = &lds[p][0];
    float* dstB = dst + BM * BD;
#pragma unroll
    for (int r = 0; r < 2; ++r) {
      int t2 = r * NT + tid;
      glds16(x + (size_t)(r0 + r * 64 + sub) * 256 + d0 + cho, dst + t2 * 4);
    }
#pragma unroll
    for (int r = 0; r < 4; ++r) {
      int t2 = r * NT + tid;
      glds16(cb + (size_t)(n0 + r * 64 + sub) * 256 + d0 + cho, dstB + t2 * 4);
    }
  };
  stage(0, 0, 0);
  int t = 0;
  for (int nt = 0; nt < 4; ++nt) {
    float acc[8][8];
#pragma unroll
    for (int i = 0; i < 8; ++i)
#pragma unroll
      for (int j = 0; j < 8; ++j) acc[i][j] = 0.f;
    for (int dt = 0; dt < 8; ++dt, ++t) {
      const int p = t & 1;
      if (t < 31) {
        const int t1 = t + 1;
        stage((t1 >> 3) * BN, (t1 & 7) * BD, t1 & 1);
        asm volatile("s_waitcnt vmcnt(6)" ::: "memory");
      } else {
        asm volatile("s_waitcnt vmcnt(0)" ::: "memory");
      }
      __builtin_amdgcn_s_barrier();
      const float* pA = &lds[p][tr * 8 * BD];
      const float* pB = &lds[p][BM * BD + tc * 8 * BD];
#pragma unroll
      for (int cc = 0; cc < 8; ++cc) {
        const float* pBc = pB + ((cc ^ sAB) << 2);
        float4 a[8], b[8];
#pragma unroll
        for (int i = 0; i < 8; ++i)
          a[i] = *reinterpret_cast<const float4*>(pA + i * BD + cc * 4);
#pragma unroll
        for (int j = 0; j < 8; ++j)
          b[j] = *reinterpret_cast<const float4*>(pBc + j * BD);
#pragma unroll
        for (int i = 0; i < 8; ++i)
#pragma unroll
          for (int j = 0; j < 8; ++j) {
            acc[i][j] = fmaf(a[i].x, b[j].x, acc[i][j]);
            acc[i][j] = fmaf(a[i].y, b[j].y, acc[i][j]);
            acc[i][j] = fmaf(a[i].z, b[j].z, acc[i][j]);
            acc[i][j] = fmaf(a[i].w, b[j].w, acc[i][j]);
          }
      }
      asm volatile("s_waitcnt lgkmcnt(0)" ::: "memory");
      __builtin_amdgcn_s_barrier();
    }
    const int n0 = nt * BN;
#pragma unroll
    for (int j = 0; j < 8; ++j) {
      const int code = n0 + tc * 8 + j;
      const float hc = c2s[code];
#pragma unroll
      for (int i = 0; i < 8; ++i) {
        float s = acc[i][j] - hc;
        if (s > bestv[i]) { bestv[i] = s; besti[i] = code; }
      }
    }
  }
#pragma unroll
  for (int i = 0; i < 8; ++i) {
#pragma unroll
    for (int m = 1; m <= 16; m <<= 1) {
      float ov = __shfl_xor(bestv[i], m, 64);
      int   oi = __shfl_xor(besti[i], m, 64);
      if (ov > bestv[i] || (ov == bestv[i] && oi < besti[i])) { bestv[i] = ov; besti[i] = oi; }
    }
  }
  if (tc == 0) {
#pragma unroll
    for (int i = 0; i < 8; ++i) out[r0 + tr * 8 + i] = besti[i];
  }
}

// ==================================== launch ====================================
extern "C" void kernel_launch(void* const* d_in, const int* in_sizes, int n_in,
                              void* d_out, int out_size, void* d_ws, size_t ws_size,
                              hipStream_t stream) {
  const float* x  = (const float*)d_in[0];   // (8,4096,256) fp32
  const float* cb = (const float*)d_in[1];   // (1024,256) fp32
  int* out = (int*)d_out;                    // (8,4096) int32

  // ws layout (bytes): cbh 512K | hc 4K | list 128K | count 4
  const size_t OFF_CH = 0;
  const size_t OFF_HC = OFF_CH + (size_t)1024 * 256 * 2;
  const size_t OFF_LS = OFF_HC + (size_t)1024 * 4;
  const size_t OFF_CT = OFF_LS + (size_t)32768 * 4;
  const size_t NEED   = OFF_CT + 64;

  if (ws_size >= NEED) {
    unsigned short* cbh = (unsigned short*)((char*)d_ws + OFF_CH);
    float* hc  = (float*)((char*)d_ws + OFF_HC);
    int* list  = (int*)((char*)d_ws + OFF_LS);
    int* count = (int*)((char*)d_ws + OFF_CT);

    hipLaunchKernelGGL(vq_prep_cb, dim3(256), dim3(256), 0, stream, cb, cbh, hc, count);
    hipLaunchKernelGGL(vq_mfma_kernel, dim3(512), dim3(512), 0, stream,
                       x, cbh, hc, out, list, count);
    hipLaunchKernelGGL(vq_cleanup, dim3(512), dim3(512), 0, stream,
                       x, cb, hc, list, count, out);
  } else {
    float* c2 = (float*)d_ws;
    hipLaunchKernelGGL(vq_c2_kernel, dim3(256), dim3(256), 0, stream, cb, c2);
    hipLaunchKernelGGL(vq_argmin_kernel, dim3(32768 / BM), dim3(NT), 0, stream,
                       x, cb, c2, out);
  }
}